// Round 1
// baseline (187.870 us; speedup 1.0000x reference)
//
#include <hip/hip_runtime.h>
#include <hip/hip_bf16.h>
#include <stdint.h>
#include <math.h>

typedef __attribute__((ext_vector_type(8))) short bf16x8;
typedef __attribute__((ext_vector_type(4))) float f32x4;

#define BM 64
#define BN 64
#define JCHUNK 1024
#define D_K 256

__device__ __forceinline__ unsigned short f2bf(float f) {
    unsigned u = __float_as_uint(f);
    u += 0x7fffu + ((u >> 16) & 1u);   // round-to-nearest-even
    return (unsigned short)(u >> 16);
}

__device__ __forceinline__ void gload_lds16(const void* g, void* l) {
    __builtin_amdgcn_global_load_lds(
        (const __attribute__((address_space(1))) void*)g,
        (__attribute__((address_space(3))) void*)l,
        16, 0, 0);
}

// ---------------- Kernel 1: row-normalize z -> bf16 ----------------
__global__ void normalize_k(const float* __restrict__ z,
                            unsigned short* __restrict__ zn, int N) {
    int gw   = (blockIdx.x * blockDim.x + threadIdx.x) >> 6;  // one wave per row
    int lane = threadIdx.x & 63;
    if (gw >= N) return;
    float4 v = reinterpret_cast<const float4*>(z + (size_t)gw * D_K)[lane];
    float ss = v.x * v.x + v.y * v.y + v.z * v.z + v.w * v.w;
#pragma unroll
    for (int m = 32; m; m >>= 1) ss += __shfl_xor(ss, m);
    float sc = 1.0f / fmaxf(sqrtf(ss), 1e-8f);
    ushort4 o;
    o.x = f2bf(v.x * sc); o.y = f2bf(v.y * sc);
    o.z = f2bf(v.z * sc); o.w = f2bf(v.w * sc);
    reinterpret_cast<ushort4*>(zn + (size_t)gw * D_K)[lane] = o;
}

// ---------------- Kernel 2: fused sim-GEMM + row reductions ----------------
// part layout: [0,N) den | [N,2N) S1 | [2N,3N) A | [3N,4N) T1 | [4N,5N) T
__global__ __launch_bounds__(256, 3) void fused_k(
    const unsigned short* __restrict__ zn,
    const float* __restrict__ adj,
    const float* __restrict__ tsim,
    float* __restrict__ part, int N) {
    __shared__ alignas(128) char Bt[BN * 512];  // 64 rows x 256 bf16 (swizzled), 32 KB

    const float INV_T = 1.0f / 0.07f;
    const int NRB = N / BM;
    int rb    = blockIdx.x % NRB;
    int jc    = blockIdx.x / NRB;
    int row0  = rb * BM;
    int jbase = jc * JCHUNK;
    int tid = threadIdx.x;
    int wid = tid >> 6, lane = tid & 63;
    int l15 = lane & 15, lhi = lane >> 4;

    // A fragments held in registers for the whole block (rows row0 + wid*16 + l15)
    bf16x8 afrag[8];
    {
        const bf16x8* ap =
            reinterpret_cast<const bf16x8*>(zn + (size_t)(row0 + wid * 16 + l15) * D_K);
#pragma unroll
        for (int ks = 0; ks < 8; ++ks) afrag[ks] = ap[ks * 4 + lhi];
    }

    const int myrowbase = row0 + wid * 16 + lhi * 4;

    float accden[4] = {0, 0, 0, 0};
    float accs1[4]  = {0, 0, 0, 0};
    float acca[4]   = {0, 0, 0, 0};
    float acct1[4]  = {0, 0, 0, 0};
    float acctt[4]  = {0, 0, 0, 0};

    for (int jt = 0; jt < JCHUNK / BN; ++jt) {
        int j0 = jbase + jt * BN;
        // ---- stage B tile: zn[j0..j0+64) x 256 bf16, XOR-swizzled via source ----
#pragma unroll
        for (int it = 0; it < 8; ++it) {
            int lb = (it * 256 + wid * 64 + lane) * 16;  // linear LDS byte per lane
            int r  = lb >> 9;
            int c  = lb & 511;
            const char* src = reinterpret_cast<const char*>(zn) +
                              ((size_t)(j0 + r) << 9) + (size_t)(c ^ ((r & 7) << 4));
            gload_lds16(src, Bt + it * 4096 + wid * 1024);  // wave-uniform dest base
        }
        asm volatile("s_waitcnt vmcnt(0)" ::: "memory");
        __syncthreads();

        // ---- MFMA: 16x16 tiles, K=256 ----
        f32x4 acc[4];
#pragma unroll
        for (int t = 0; t < 4; ++t) acc[t] = (f32x4){0.f, 0.f, 0.f, 0.f};
#pragma unroll
        for (int ks = 0; ks < 8; ++ks) {
            bf16x8 bfr[4];
#pragma unroll
            for (int t = 0; t < 4; ++t) {
                int brow = t * 16 + l15;
                int boff = (brow << 9) + (((ks << 6) + (lhi << 4)) ^ ((brow & 7) << 4));
                bfr[t] = *reinterpret_cast<const bf16x8*>(Bt + boff);
            }
#pragma unroll
            for (int t = 0; t < 4; ++t)
                acc[t] = __builtin_amdgcn_mfma_f32_16x16x32_bf16(afrag[ks], bfr[t], acc[t], 0, 0, 0);
        }

        // ---- epilogue: exp, mask diag, stream adj/tsim, accumulate row sums ----
#pragma unroll
        for (int t = 0; t < 4; ++t) {
            int gcol = j0 + t * 16 + l15;
#pragma unroll
            for (int r = 0; r < 4; ++r) {
                int grow = myrowbase + r;
                size_t off = (size_t)grow * N + gcol;
                float sim = acc[t][r] * INV_T;
                float e   = (grow == gcol) ? 0.f : __expf(sim);
                float av  = __builtin_nontemporal_load(adj + off);
                float tv  = __builtin_nontemporal_load(tsim + off);
                accden[r] += e;
                accs1[r] = fmaf(av, sim, accs1[r]);
                acca[r] += av;
                acct1[r] = fmaf(tv, sim, acct1[r]);
                acctt[r] += tv;
            }
        }
        __syncthreads();  // protect LDS before next stage
    }

    // ---- reduce across the 16 fragment columns, one atomic per row ----
#pragma unroll
    for (int r = 0; r < 4; ++r) {
        float d = accden[r], s = accs1[r], a = acca[r], u = acct1[r], w = acctt[r];
#pragma unroll
        for (int m = 1; m < 16; m <<= 1) {
            d += __shfl_xor(d, m); s += __shfl_xor(s, m); a += __shfl_xor(a, m);
            u += __shfl_xor(u, m); w += __shfl_xor(w, m);
        }
        if (l15 == 0) {
            int grow = myrowbase + r;
            atomicAdd(part + grow, d);
            atomicAdd(part + (size_t)N + grow, s);
            atomicAdd(part + (size_t)2 * N + grow, a);
            atomicAdd(part + (size_t)3 * N + grow, u);
            atomicAdd(part + (size_t)4 * N + grow, w);
        }
    }
}

// ---------------- Kernel 3: finalize scalar ----------------
__global__ void finalize_k(const float* __restrict__ part, float* __restrict__ out, int N) {
    const float* den = part;
    const float* s1  = part + (size_t)N;
    const float* aa  = part + (size_t)2 * N;
    const float* t1  = part + (size_t)3 * N;
    const float* tt  = part + (size_t)4 * N;
    float acc = 0.f;
    for (int i = threadIdx.x; i < N; i += blockDim.x) {
        float ld = logf(den[i] + 1e-8f);
        acc += -(s1[i] - ld * aa[i]) / (aa[i] + 1e-8f)
               - (t1[i] - ld * tt[i]) / (tt[i] + 1e-8f);
    }
#pragma unroll
    for (int m = 32; m; m >>= 1) acc += __shfl_xor(acc, m);
    __shared__ float red[16];
    if ((threadIdx.x & 63) == 0) red[threadIdx.x >> 6] = acc;
    __syncthreads();
    if (threadIdx.x == 0) {
        float tot = 0.f;
        int nw = blockDim.x >> 6;
        for (int w = 0; w < nw; ++w) tot += red[w];
        out[0] = tot / (float)N;
    }
}

extern "C" void kernel_launch(void* const* d_in, const int* in_sizes, int n_in,
                              void* d_out, int out_size, void* d_ws, size_t ws_size,
                              hipStream_t stream) {
    const float* z    = (const float*)d_in[0];
    const float* adj  = (const float*)d_in[1];
    const float* tsim = (const float*)d_in[2];

    int N = (int)(sqrt((double)in_sizes[1]) + 0.5);  // 8192
    // D fixed at 256 (asserted by problem shapes)

    unsigned short* zn = (unsigned short*)d_ws;                       // N*256 bf16 = 4 MB
    float* part = (float*)((char*)d_ws + (size_t)N * D_K * 2);        // 5*N f32

    hipMemsetAsync(part, 0, (size_t)5 * N * sizeof(float), stream);

    normalize_k<<<N / 4, 256, 0, stream>>>(z, zn, N);

    int nblocks = (N / BM) * (N / JCHUNK);  // 128 * 8 = 1024
    fused_k<<<nblocks, 256, 0, stream>>>(zn, adj, tsim, part, N);

    finalize_k<<<1, 1024, 0, stream>>>(part, (float*)d_out, N);
}